// Round 18
// baseline (141.329 us; speedup 1.0000x reference)
//
#include <hip/hip_runtime.h>
#include <hip/hip_bf16.h>
#include <math.h>

// B=4, T=S=512, M=N=512, H=128
#define KDIM 512
#define HDIM 128
#define SDIM 512
#define TOTAL_ROWS 2048
#define PROJ_REPS 16     // DIAGNOSTIC: repeat proj body to surface it in rocprof top-5
#define INV_SCALE 0.04419417382415922f   // 1/sqrt(512)

// score[b,t,s] = a'[b,t] + c'[b,s]  (both pre-scaled)
// ws: [0,2048) a' f32; [2048,4096) c' f32.
// D1: r17 proj (both sides, K-half pipelined), body repeated PROJ_REPS times.
// D2: outer broadcast-add (r13/r17 verbatim).

typedef __attribute__((ext_vector_type(8))) short bf16x8;   // 8 bf16 = 4 VGPRs
typedef __attribute__((ext_vector_type(4))) float f32x4;    // MFMA accumulator

__device__ __forceinline__ float fast_tanh(float x) {
    // tanh(x) = 1 - 2/(e^{2x}+1); ~1e-7 abs error, graceful at +/-inf
    float e = __expf(2.0f * x);
    return 1.0f - 2.0f / (e + 1.0f);
}
__device__ __forceinline__ unsigned short bfbits(float x) {
    return __builtin_bit_cast(unsigned short, __float2bfloat16(x));
}
__device__ __forceinline__ bf16x8 cvt8(const float4 p, const float4 q) {
    bf16x8 r;
    r[0] = (short)bfbits(p.x); r[1] = (short)bfbits(p.y);
    r[2] = (short)bfbits(p.z); r[3] = (short)bfbits(p.w);
    r[4] = (short)bfbits(q.x); r[5] = (short)bfbits(q.y);
    r[6] = (short)bfbits(q.z); r[7] = (short)bfbits(q.w);
    return r;
}

// Stage one K-half of the X tile into LDS (k-bijection granule layout, r17).
__device__ __forceinline__ void stage_half(
    unsigned short* sm_x, const float4 xv, int fhalf, int halfsel)
{
    const int row  = fhalf >> 6;
    const int fr   = fhalf & 63;
    const int s    = (fr >> 3) + halfsel * 8;   // global 32-k step
    const int off4 = fr & 7;
    const int g    = off4 & 3;
    const int half = off4 >> 2;
    ushort4 o;
    o.x = bfbits(xv.x); o.y = bfbits(xv.y);
    o.z = bfbits(xv.z); o.w = bfbits(xv.w);
    char* dst = (char*)sm_x + row * 1024 + (((s * 4 + g) ^ (row & 7)) << 4) + half * 8;
    *(ushort4*)dst = o;
}

// r17 proj with a diagnostic rep-loop. Output identical every iteration.
__global__ __launch_bounds__(512) void proj_kernel(
    const float* __restrict__ query, const float* __restrict__ keys,
    const float* __restrict__ W1, const float* __restrict__ W2,
    const float* __restrict__ v, float* __restrict__ ws, int reps)
{
    const int blk = blockIdx.x;
    const bool is_keys = (blk >= 128);
    const float* __restrict__ X  = is_keys ? keys : query;
    const float* __restrict__ Wf = is_keys ? W1 : W2;
    const float* __restrict__ vv = v + (is_keys ? HDIM : 0);
    float* __restrict__ out = ws + (is_keys ? TOTAL_ROWS : 0);
    const int row0 = (blk & 127) * 16;

    __shared__ __align__(16) unsigned short sm_x[16 * KDIM];  // 16 KB bf16
    __shared__ float sm_p[8][16];

    const int tid  = threadIdx.x;
    const int wave = tid >> 6;
    const int lane = tid & 63;

    for (int it = 0; it < reps; ++it) {
        // opaque zero: prevents cross-iteration CSE of the whole body
        int z;
        asm volatile("v_mov_b32 %0, 0" : "=v"(z));
        const float* __restrict__ Xe = X + z;
        const float* __restrict__ We = Wf + z;

        const float4* __restrict__ xsrc = (const float4*)(Xe + (size_t)row0 * KDIM);

        // ---- Phase A stage: k in [0,256) for all 16 rows (1024 float4, 2/thread). ----
        {
            const int f0 = tid, f1 = tid + 512;
            const float4 xa0 = xsrc[(f0 >> 6) * 128 + (f0 & 63)];
            const float4 xa1 = xsrc[(f1 >> 6) * 128 + (f1 & 63)];
            stage_half(sm_x, xa0, f0, 0);
            stage_half(sm_x, xa1, f1, 0);
        }
        __syncthreads();

        // ---- Issue Phase B loads now (k in [256,512)); consumed after loop A. ----
        const int f0 = tid, f1 = tid + 512;
        const float4 xb0 = xsrc[(f0 >> 6) * 128 + 64 + (f0 & 63)];
        const float4 xb1 = xsrc[(f1 >> 6) * 128 + 64 + (f1 & 63)];

        const int c16 = lane & 15;
        const int g   = lane >> 4;
        const int h0  = wave * 16;
        const float* __restrict__ wrow = We + (size_t)(h0 + c16) * KDIM + g * 4;
        const char* __restrict__ arow = (const char*)sm_x + c16 * 1024;
        const int swz = c16 & 7;

        f32x4 acc = {0.0f, 0.0f, 0.0f, 0.0f};

        // ---- Loop A: K-steps 0-7 (k 0-255). ----
        #pragma unroll
        for (int t = 0; t < 8; ++t) {
            const float4 b0 = *(const float4*)(wrow + t * 32);
            const float4 b1 = *(const float4*)(wrow + t * 32 + 16);
            const bf16x8 a = *(const bf16x8*)(arow + (((t * 4 + g) ^ swz) << 4));
            acc = __builtin_amdgcn_mfma_f32_16x16x32_bf16(a, cvt8(b0, b1), acc, 0, 0, 0);
        }

        // ---- Phase B stage (disjoint LDS region). ----
        stage_half(sm_x, xb0, f0, 1);
        stage_half(sm_x, xb1, f1, 1);
        __syncthreads();

        // ---- Loop B: K-steps 8-15 (k 256-511). ----
        #pragma unroll
        for (int t = 8; t < 16; ++t) {
            const float4 b0 = *(const float4*)(wrow + t * 32);
            const float4 b1 = *(const float4*)(wrow + t * 32 + 16);
            const bf16x8 a = *(const bf16x8*)(arow + (((t * 4 + g) ^ swz) << 4));
            acc = __builtin_amdgcn_mfma_f32_16x16x32_bf16(a, cvt8(b0, b1), acc, 0, 0, 0);
        }

        // ---- Epilogue ----
        const float vh = vv[h0 + c16];
        #pragma unroll
        for (int r = 0; r < 4; ++r) {
            float s = vh * fast_tanh(acc[r]);
            s += __shfl_xor(s, 1, 64);
            s += __shfl_xor(s, 2, 64);
            s += __shfl_xor(s, 4, 64);
            s += __shfl_xor(s, 8, 64);
            if (c16 == 0) sm_p[wave][g * 4 + r] = s;
        }
        __syncthreads();

        if (tid < 16) {
            float s = 0.0f;
            #pragma unroll
            for (int w = 0; w < 8; ++w) s += sm_p[w][tid];
            out[row0 + tid] = s * INV_SCALE;
        }
        __syncthreads();
        asm volatile("" ::: "memory");
    }
}

// 256 blocks x 256 thr; block = 8 bt-rows (single batch each). c' row stays L1-hot.
__global__ __launch_bounds__(256) void outer_kernel(
    const float* __restrict__ ws, float* __restrict__ out)
{
    const int r0  = blockIdx.x * 8;
    const int b   = r0 >> 9;
    const float4* __restrict__ c4 = (const float4*)(ws + TOTAL_ROWS + (size_t)b * SDIM);
    const int col = threadIdx.x & 127;
    const int rh  = threadIdx.x >> 7;   // 0/1

    #pragma unroll
    for (int rp = 0; rp < 4; ++rp) {
        const int row = r0 + rp * 2 + rh;
        const float a = ws[row];
        const float4 c = c4[col];
        float4 o;
        o.x = a + c.x; o.y = a + c.y; o.z = a + c.z; o.w = a + c.w;
        ((float4*)out)[(size_t)row * (SDIM / 4) + col] = o;
    }
}

extern "C" void kernel_launch(void* const* d_in, const int* in_sizes, int n_in,
                              void* d_out, int out_size, void* d_ws, size_t ws_size,
                              hipStream_t stream) {
    const float* query = (const float*)d_in[0];  // (4,512,512)
    const float* keys  = (const float*)d_in[1];  // (4,512,512)
    const float* W1    = (const float*)d_in[2];  // (128,512)
    const float* W2    = (const float*)d_in[3];  // (128,512)
    const float* v     = (const float*)d_in[4];  // (1,256)
    float* out = (float*)d_out;                  // (4,512,512) f32
    float* ws  = (float*)d_ws;                   // a' + c' (4096 floats)

    proj_kernel<<<256, 512, 0, stream>>>(query, keys, W1, W2, v, ws, PROJ_REPS);
    outer_kernel<<<256, 256, 0, stream>>>(ws, out);
}

// Round 19
// 17.394 us; speedup vs baseline: 8.1250x; 8.1250x over previous
//
#include <hip/hip_runtime.h>
#include <hip/hip_bf16.h>
#include <math.h>

// B=4, T=S=512, M=N=512, H=128
#define KDIM 512
#define HDIM 128
#define SDIM 512
#define TOTAL_ROWS 2048
#define INV_SCALE 0.04419417382415922f   // 1/sqrt(512)

// score[b,t,s] = a'[b,t] + c'[b,s]  (both pre-scaled)
// ws: [0,2048) a' f32; [2048,4096) c' f32.
// D1: proj both sides; ALL 32 W float4s preloaded into registers up-front
//     (r18 diagnosis: VGPR=32 build serialized one ~200cyc L2 round-trip per
//     MFMA step -> 8.3 us; deep vmcnt pipeline turns W into a BW-bound stream).
// D2: outer broadcast-add.

typedef __attribute__((ext_vector_type(8))) short bf16x8;   // 8 bf16 = 4 VGPRs
typedef __attribute__((ext_vector_type(4))) float f32x4;    // MFMA accumulator

__device__ __forceinline__ float fast_tanh(float x) {
    // tanh(x) = 1 - 2/(e^{2x}+1); ~1e-7 abs error, graceful at +/-inf
    float e = __expf(2.0f * x);
    return 1.0f - 2.0f / (e + 1.0f);
}
__device__ __forceinline__ unsigned short bfbits(float x) {
    return __builtin_bit_cast(unsigned short, __float2bfloat16(x));
}
__device__ __forceinline__ bf16x8 cvt8(const float4 p, const float4 q) {
    bf16x8 r;
    r[0] = (short)bfbits(p.x); r[1] = (short)bfbits(p.y);
    r[2] = (short)bfbits(p.z); r[3] = (short)bfbits(p.w);
    r[4] = (short)bfbits(q.x); r[5] = (short)bfbits(q.y);
    r[6] = (short)bfbits(q.z); r[7] = (short)bfbits(q.w);
    return r;
}

// Stage one K-half of the X tile into LDS (k-bijection granule layout, r17).
__device__ __forceinline__ void stage_half(
    unsigned short* sm_x, const float4 xv, int fhalf, int halfsel)
{
    const int row  = fhalf >> 6;
    const int fr   = fhalf & 63;
    const int s    = (fr >> 3) + halfsel * 8;   // global 32-k step
    const int off4 = fr & 7;
    const int g    = off4 & 3;
    const int half = off4 >> 2;
    ushort4 o;
    o.x = bfbits(xv.x); o.y = bfbits(xv.y);
    o.z = bfbits(xv.z); o.w = bfbits(xv.w);
    char* dst = (char*)sm_x + row * 1024 + (((s * 4 + g) ^ (row & 7)) << 4) + half * 8;
    *(ushort4*)dst = o;
}

// 256 blocks x 512 thr (8 waves): blk<128 query w/ W2 -> ws[0:2048);
// blk>=128 keys w/ W1 -> ws[2048:4096). 16 rows/block; wave = h-tile h0=16*wave.
// Load order: 4 X loads -> 32 W loads (all in flight) -> stage X (waits only on X,
// ds_writes overlap the W stream) -> barrier (drains W at L2 BW) -> 16 MFMA steps
// from registers+LDS. k-bijection (r11/r13-verified); C: col=lane&15, row=g*4+reg.
__global__ __launch_bounds__(512, 1) void proj_kernel(
    const float* __restrict__ query, const float* __restrict__ keys,
    const float* __restrict__ W1, const float* __restrict__ W2,
    const float* __restrict__ v, float* __restrict__ ws)
{
    const int blk = blockIdx.x;
    const bool is_keys = (blk >= 128);
    const float* __restrict__ X  = is_keys ? keys : query;
    const float* __restrict__ Wf = is_keys ? W1 : W2;
    const float* __restrict__ vv = v + (is_keys ? HDIM : 0);
    float* __restrict__ out = ws + (is_keys ? TOTAL_ROWS : 0);
    const int row0 = (blk & 127) * 16;

    __shared__ __align__(16) unsigned short sm_x[16 * KDIM];  // 16 KB bf16
    __shared__ float sm_p[8][16];

    const int tid  = threadIdx.x;
    const int wave = tid >> 6;
    const int lane = tid & 63;
    const int c16  = lane & 15;
    const int g    = lane >> 4;
    const int h0   = wave * 16;

    const float4* __restrict__ xsrc = (const float4*)(X + (size_t)row0 * KDIM);
    const float* __restrict__ wrow = Wf + (size_t)(h0 + c16) * KDIM + g * 4;

    // ---- Issue X loads FIRST (oldest in vmem queue: stage waits only on these). ----
    const int f0 = tid, f1 = tid + 512;
    const float4 xa0 = xsrc[(f0 >> 6) * 128 + (f0 & 63)];
    const float4 xa1 = xsrc[(f1 >> 6) * 128 + (f1 & 63)];
    const float4 xb0 = xsrc[(f0 >> 6) * 128 + 64 + (f0 & 63)];
    const float4 xb1 = xsrc[(f1 >> 6) * 128 + 64 + (f1 & 63)];

    // ---- Issue ALL W loads (32 dwordx4, static register array, full unroll). ----
    float4 wreg0[16], wreg1[16];
    #pragma unroll
    for (int t = 0; t < 16; ++t) {
        wreg0[t] = *(const float4*)(wrow + t * 32);        // k t*32+g*4..+3
        wreg1[t] = *(const float4*)(wrow + t * 32 + 16);   // k t*32+16+g*4..+3
    }

    // ---- Stage X tile (consumes only the 4 X loads; overlaps the W stream). ----
    stage_half(sm_x, xa0, f0, 0);
    stage_half(sm_x, xa1, f1, 0);
    stage_half(sm_x, xb0, f0, 1);
    stage_half(sm_x, xb1, f1, 1);
    __syncthreads();

    const char* __restrict__ arow = (const char*)sm_x + c16 * 1024;
    const int swz = c16 & 7;

    f32x4 acc = {0.0f, 0.0f, 0.0f, 0.0f};
    #pragma unroll
    for (int t = 0; t < 16; ++t) {
        const bf16x8 a = *(const bf16x8*)(arow + (((t * 4 + g) ^ swz) << 4));
        acc = __builtin_amdgcn_mfma_f32_16x16x32_bf16(a, cvt8(wreg0[t], wreg1[t]),
                                                      acc, 0, 0, 0);
    }

    // acc[r] = dot(X[row0+g*4+r], W[h0+c16]); weight by v, tanh, reduce over h.
    const float vh = vv[h0 + c16];
    #pragma unroll
    for (int r = 0; r < 4; ++r) {
        float s = vh * fast_tanh(acc[r]);
        s += __shfl_xor(s, 1, 64);   // reduce over h-columns (lane bits 0-3)
        s += __shfl_xor(s, 2, 64);
        s += __shfl_xor(s, 4, 64);
        s += __shfl_xor(s, 8, 64);
        if (c16 == 0) sm_p[wave][g * 4 + r] = s;
    }
    __syncthreads();

    if (tid < 16) {
        float s = 0.0f;
        #pragma unroll
        for (int w = 0; w < 8; ++w) s += sm_p[w][tid];
        out[row0 + tid] = s * INV_SCALE;
    }
}

// 256 blocks x 256 thr; block = 8 bt-rows (single batch each). c' row stays L1-hot.
__global__ __launch_bounds__(256) void outer_kernel(
    const float* __restrict__ ws, float* __restrict__ out)
{
    const int r0  = blockIdx.x * 8;
    const int b   = r0 >> 9;
    const float4* __restrict__ c4 = (const float4*)(ws + TOTAL_ROWS + (size_t)b * SDIM);
    const int col = threadIdx.x & 127;
    const int rh  = threadIdx.x >> 7;   // 0/1

    #pragma unroll
    for (int rp = 0; rp < 4; ++rp) {
        const int row = r0 + rp * 2 + rh;
        const float a = ws[row];
        const float4 c = c4[col];
        float4 o;
        o.x = a + c.x; o.y = a + c.y; o.z = a + c.z; o.w = a + c.w;
        ((float4*)out)[(size_t)row * (SDIM / 4) + col] = o;
    }
}

extern "C" void kernel_launch(void* const* d_in, const int* in_sizes, int n_in,
                              void* d_out, int out_size, void* d_ws, size_t ws_size,
                              hipStream_t stream) {
    const float* query = (const float*)d_in[0];  // (4,512,512)
    const float* keys  = (const float*)d_in[1];  // (4,512,512)
    const float* W1    = (const float*)d_in[2];  // (128,512)
    const float* W2    = (const float*)d_in[3];  // (128,512)
    const float* v     = (const float*)d_in[4];  // (1,256)
    float* out = (float*)d_out;                  // (4,512,512) f32
    float* ws  = (float*)d_ws;                   // a' + c' (4096 floats)

    proj_kernel<<<256, 512, 0, stream>>>(query, keys, W1, W2, v, ws);
    outer_kernel<<<256, 256, 0, stream>>>(ws, out);
}